// Round 11
// baseline (60.644 us; speedup 1.0000x reference)
//
#include <hip/hip_runtime.h>
#include <math.h>

#define B 4
#define TQ 512
#define TV 1024
#define DQ 256
#define DV 256
#define UNITS 64
#define NQROW (B * TQ)   // 2048
#define NKROW (B * TV)   // 4096

#define CEXP  2.885390081777927f    // 2*log2(e): exp(2x) == exp2(CEXP*x)
#define LOG2E 1.4426950408889634f

__device__ __forceinline__ float fast_exp2(float x) {
#if __has_builtin(__builtin_amdgcn_exp2f)
    return __builtin_amdgcn_exp2f(x);
#else
    return __expf(0.6931471805599453f * x);
#endif
}

__device__ __forceinline__ float wave_sum(float v) {
    #pragma unroll
    for (int off = 32; off > 0; off >>= 1)
        v += __shfl_xor(v, off, 64);
    return v;
}

// ---- projections: 8-way d-split, 512 thr, grid 768 (6 waves/SIMD) ----
// 8 rows/block staged in LDS; wave wid covers c in [wid*8, wid*8+8).
#define RPB 8
__global__ __launch_bounds__(512) void proj_kernel(
        const float* __restrict__ query, const float* __restrict__ value,
        const float* __restrict__ w1, const float* __restrict__ w2,
        float* __restrict__ Eq, float* __restrict__ EkT) {
    __shared__ float rows[RPB][DQ];            // 8 KB
    __shared__ float part[8][RPB][UNITS + 2];  // ~16.9 KB, padded
    const int tid = threadIdx.x;
    const int u   = tid & 63;
    const int wid = tid >> 6;                  // 0..7 -> d-range
    const int row0 = blockIdx.x * RPB;
    const bool isq = row0 < NQROW;
    const float* in = isq ? query + (size_t)row0 * DQ
                          : value + (size_t)(row0 - NQROW) * DQ;
    const float* w  = isq ? w1 : w2;

    // stage 8 rows (2048 floats): one float4 per thread
    ((float4*)&rows[0][0])[tid] = ((const float4*)in)[tid];
    __syncthreads();

    float a[RPB] = {};
    const int c0 = wid * 8;
    #pragma unroll
    for (int ci = 0; ci < 8; ++ci) {
        const int c = c0 + ci;
        const float w0v = w[(4 * c + 0) * UNITS + u];
        const float w1v = w[(4 * c + 1) * UNITS + u];
        const float w2v = w[(4 * c + 2) * UNITS + u];
        const float w3v = w[(4 * c + 3) * UNITS + u];
        #pragma unroll
        for (int r = 0; r < RPB; ++r) {
            const float4 t = *(const float4*)&rows[r][4 * c];
            a[r] = fmaf(t.x, w0v, a[r]);
            a[r] = fmaf(t.y, w1v, a[r]);
            a[r] = fmaf(t.z, w2v, a[r]);
            a[r] = fmaf(t.w, w3v, a[r]);
        }
    }
    #pragma unroll
    for (int r = 0; r < RPB; ++r)
        part[wid][r][u] = a[r];
    __syncthreads();

    if (isq) {
        const int row = tid >> 6, uu = tid & 63;
        const float s = ((part[0][row][uu] + part[1][row][uu]) +
                         (part[2][row][uu] + part[3][row][uu])) +
                        ((part[4][row][uu] + part[5][row][uu]) +
                         (part[6][row][uu] + part[7][row][uu]));
        Eq[(size_t)(row0 + row) * UNITS + uu] = fast_exp2(CEXP * s);
    } else {
        const int uu = tid >> 3, r = tid & 7;
        const float s = ((part[0][r][uu] + part[1][r][uu]) +
                         (part[2][r][uu] + part[3][r][uu])) +
                        ((part[4][r][uu] + part[5][r][uu]) +
                         (part[6][r][uu] + part[7][r][uu]));
        EkT[(size_t)uu * NKROW + (row0 - NQROW) + r] = fast_exp2(CEXP * s);
    }
}

// ---- scores + softmax: QB=2, grid 1024 (8 waves/SIMD, occupancy cap) ----
#define QB 2
#define SNT 512
#define SNW (SNT / 64)
// thread owns v = {2*tid, 2*tid+1}
__global__ __launch_bounds__(SNT) void score_kernel(
        const float* __restrict__ Eq,      // [NQROW][UNITS]
        const float* __restrict__ EkT,     // [UNITS][NKROW]
        const float* __restrict__ scale,   // [UNITS]
        float* __restrict__ out_attn) {    // [NQROW][TV]
    __shared__ float q_lds[QB][UNITS];
    __shared__ float s_lds[UNITS];
    __shared__ float reds[QB][SNW];

    const int tid = threadIdx.x, lane = tid & 63, wid = tid >> 6;
    int bid = blockIdx.x;
    bid = (bid & 7) * ((NQROW / QB) >> 3) + (bid >> 3);   // XCD swizzle, bijective
    const int b  = bid / (TQ / QB);
    const int q0 = (bid % (TQ / QB)) * QB;

    if (tid < QB * UNITS)
        q_lds[tid >> 6][tid & 63] =
            Eq[(size_t)(b * TQ + q0 + (tid >> 6)) * UNITS + (tid & 63)];
    else if (tid < QB * UNITS + UNITS)
        s_lds[tid - QB * UNITS] = scale[tid - QB * UNITS];
    __syncthreads();

    const float* ekc = EkT + (size_t)b * TV + 2 * tid;
    float acc0[QB] = {}, acc1[QB] = {};

    #pragma unroll 4
    for (int u4 = 0; u4 < UNITS / 4; ++u4) {
        const float2 ek0 = *(const float2*)(ekc + (size_t)(4 * u4 + 0) * NKROW);
        const float2 ek1 = *(const float2*)(ekc + (size_t)(4 * u4 + 1) * NKROW);
        const float2 ek2 = *(const float2*)(ekc + (size_t)(4 * u4 + 2) * NKROW);
        const float2 ek3 = *(const float2*)(ekc + (size_t)(4 * u4 + 3) * NKROW);
        const float4 s4 = *(const float4*)(s_lds + 4 * u4);
        #pragma unroll
        for (int q = 0; q < QB; ++q) {
            const float4 eq = *(const float4*)(&q_lds[q][4 * u4]);
            {   // v0: sum_{i=0..3} s_i / t_i with one rcp
                float t0 = fmaf(eq.x, ek0.x, 1.f);
                float t1 = fmaf(eq.y, ek1.x, 1.f);
                float t2 = fmaf(eq.z, ek2.x, 1.f);
                float t3 = fmaf(eq.w, ek3.x, 1.f);
                float p01 = t0 * t1, p23 = t2 * t3;
                float A  = fmaf(s4.y, t0, s4.x * t1);
                float Bq = fmaf(s4.w, t2, s4.z * t3);
                float num = fmaf(Bq, p01, A * p23);
                float r = __builtin_amdgcn_rcpf(p01 * p23);
                acc0[q] = fmaf(num, r, acc0[q]);
            }
            {   // v1
                float t0 = fmaf(eq.x, ek0.y, 1.f);
                float t1 = fmaf(eq.y, ek1.y, 1.f);
                float t2 = fmaf(eq.z, ek2.y, 1.f);
                float t3 = fmaf(eq.w, ek3.y, 1.f);
                float p01 = t0 * t1, p23 = t2 * t3;
                float A  = fmaf(s4.y, t0, s4.x * t1);
                float Bq = fmaf(s4.w, t2, s4.z * t3);
                float num = fmaf(Bq, p01, A * p23);
                float r = __builtin_amdgcn_rcpf(p01 * p23);
                acc1[q] = fmaf(num, r, acc1[q]);
            }
        }
    }

    // no-max softmax: e = exp2(-2*acc*LOG2E) directly (range-safe)
    float e0[QB], e1[QB];
    #pragma unroll
    for (int q = 0; q < QB; ++q) {
        e0[q] = fast_exp2(-2.f * LOG2E * acc0[q]);
        e1[q] = fast_exp2(-2.f * LOG2E * acc1[q]);
        float s = wave_sum(e0[q] + e1[q]);
        if (lane == 0) reds[q][wid] = s;
    }
    __syncthreads();
    #pragma unroll
    for (int q = 0; q < QB; ++q) {
        float ss = reds[q][0];
        #pragma unroll
        for (int i = 1; i < SNW; ++i) ss += reds[q][i];
        const float inv = __builtin_amdgcn_rcpf(ss);
        float2 o; o.x = e0[q] * inv; o.y = e1[q] * inv;
        float* arow = out_attn + (size_t)(b * TQ + q0 + q) * TV;
        *(float2*)(arow + 2 * tid) = o;
    }
}

// ---- context partial: QC q-rows x TV/SPLIT v-range per block ----
template <int QC, int SPLIT>
__global__ __launch_bounds__(512) void ctx_kernel(
        const float* __restrict__ attn,    // [NQROW][TV]
        const float* __restrict__ value,   // [B][TV][DV]
        float* __restrict__ dst) {         // [SPLIT][NQROW][DV]
    constexpr int TVC = TV / SPLIT;
    constexpr int QT  = QC / 2;            // q rows per thread (512 thr / 256 d)
    const int tid = threadIdx.x;
    constexpr int G = (NQROW / QC) * SPLIT;
    int bid = blockIdx.x;
    bid = (bid & 7) * (G >> 3) + (bid >> 3);   // XCD swizzle (G % 8 == 0)
    const int qc = bid / SPLIT, vs = bid % SPLIT;
    const int b  = qc / (TQ / QC);
    const int q0 = (qc % (TQ / QC)) * QC;
    const int v0 = vs * TVC;
    const int d  = tid & (DV - 1);
    const int qh = __builtin_amdgcn_readfirstlane(tid >> 8) * QT;

    const float* ab = attn + (size_t)(b * TQ + q0 + qh) * TV + v0;
    const float* vb = value + ((size_t)b * TV + v0) * DV + d;

    float acc[QT] = {};
    #pragma unroll 2
    for (int v4 = 0; v4 < TVC / 4; ++v4) {
        float4 aq[QT];
        #pragma unroll
        for (int j = 0; j < QT; ++j)
            aq[j] = *(const float4*)(ab + (size_t)j * TV + v4 * 4);
        #pragma unroll
        for (int k = 0; k < 4; ++k) {
            float val = vb[(size_t)(v4 * 4 + k) * DV];
            #pragma unroll
            for (int j = 0; j < QT; ++j)
                acc[j] = fmaf(((const float*)&aq[j])[k], val, acc[j]);
        }
    }
    float* o = dst + (size_t)vs * (NQROW * DV) + (size_t)(b * TQ + q0 + qh) * DV + d;
    #pragma unroll
    for (int j = 0; j < QT; ++j)
        o[(size_t)j * DV] = acc[j];
}

// out[i] = sum over NP partials
template <int NP>
__global__ __launch_bounds__(256) void reduce_kernel(
        const float* __restrict__ part, float* __restrict__ out) {
    constexpr size_t S = (size_t)NQROW * DV / 4;   // float4 count per partial
    const size_t i = (size_t)blockIdx.x * 256 + threadIdx.x;
    const float4* p = (const float4*)part;
    float4 r = p[i];
    #pragma unroll
    for (int k = 1; k < NP; ++k) {
        float4 t = p[i + (size_t)k * S];
        r.x += t.x; r.y += t.y; r.z += t.z; r.w += t.w;
    }
    ((float4*)out)[i] = r;
}

extern "C" void kernel_launch(void* const* d_in, const int* in_sizes, int n_in,
                              void* d_out, int out_size, void* d_ws, size_t ws_size,
                              hipStream_t stream) {
    const float* query = (const float*)d_in[0];
    const float* value = (const float*)d_in[1];
    const float* w1    = (const float*)d_in[2];
    const float* w2    = (const float*)d_in[3];
    const float* scale = (const float*)d_in[4];

    float* out      = (float*)d_out;
    float* out_ctx  = out;                         // [NQROW*DV]
    float* out_attn = out + (size_t)NQROW * DV;    // [NQROW*TV]

    float* Eq   = (float*)d_ws;                    // NQROW*UNITS
    float* EkT  = Eq + (size_t)NQROW * UNITS;      // UNITS*NKROW
    float* part = EkT + (size_t)UNITS * NKROW;     // 8 * NQROW*DV

    const size_t need = ((size_t)NQROW * UNITS + (size_t)UNITS * NKROW +
                         (size_t)8 * NQROW * DV) * sizeof(float);

    proj_kernel<<<dim3((NQROW + NKROW) / RPB), 512, 0, stream>>>(
        query, value, w1, w2, Eq, EkT);
    score_kernel<<<dim3(NQROW / QB), SNT, 0, stream>>>(Eq, EkT, scale, out_attn);
    if (ws_size >= need) {
        ctx_kernel<8, 8><<<dim3((NQROW / 8) * 8), 512, 0, stream>>>(out_attn, value, part);
        reduce_kernel<8><<<dim3(NQROW * DV / 4 / 256), 256, 0, stream>>>(part, out_ctx);
    } else {
        ctx_kernel<8, 1><<<dim3(NQROW / 8), 512, 0, stream>>>(out_attn, value, out_ctx);
    }
}

// Round 13
// 59.803 us; speedup vs baseline: 1.0141x; 1.0141x over previous
//
#include <hip/hip_runtime.h>
#include <math.h>

#define B 4
#define TQ 512
#define TV 1024
#define DQ 256
#define DV 256
#define UNITS 64
#define NQROW (B * TQ)   // 2048
#define NKROW (B * TV)   // 4096

#define CEXP  2.885390081777927f    // 2*log2(e): exp(2x) == exp2(CEXP*x)
#define LOG2E 1.4426950408889634f

__device__ __forceinline__ float fast_exp2(float x) {
#if __has_builtin(__builtin_amdgcn_exp2f)
    return __builtin_amdgcn_exp2f(x);
#else
    return __expf(0.6931471805599453f * x);
#endif
}

__device__ __forceinline__ float wave_sum(float v) {
    #pragma unroll
    for (int off = 32; off > 0; off >>= 1)
        v += __shfl_xor(v, off, 64);
    return v;
}

// ---- projections (R10 known-good): 4-way d-split, 256 thr, 8 rows/block ----
#define RPB 8
__global__ __launch_bounds__(256) void proj_kernel(
        const float* __restrict__ query, const float* __restrict__ value,
        const float* __restrict__ w1, const float* __restrict__ w2,
        float* __restrict__ Eq, float* __restrict__ EkT) {
    __shared__ float rows[RPB][DQ];            // 8 KB
    __shared__ float part[4][RPB][UNITS + 2];  // padded vs bank conflicts
    const int tid = threadIdx.x;
    const int u   = tid & 63;
    const int wid = tid >> 6;                  // 0..3 -> d-range
    const int row0 = blockIdx.x * RPB;
    const bool isq = row0 < NQROW;
    const float* in = isq ? query + (size_t)row0 * DQ
                          : value + (size_t)(row0 - NQROW) * DQ;
    const float* w  = isq ? w1 : w2;

    {   // stage 8 rows (2048 floats) coalesced
        const float4* src = (const float4*)in;
        float4* dst = (float4*)&rows[0][0];
        dst[tid]       = src[tid];
        dst[tid + 256] = src[tid + 256];
    }
    __syncthreads();

    float a[RPB] = {};
    const int c0 = wid * 16;
    #pragma unroll 4
    for (int ci = 0; ci < 16; ++ci) {
        const int c = c0 + ci;
        const float w0v = w[(4 * c + 0) * UNITS + u];
        const float w1v = w[(4 * c + 1) * UNITS + u];
        const float w2v = w[(4 * c + 2) * UNITS + u];
        const float w3v = w[(4 * c + 3) * UNITS + u];
        #pragma unroll
        for (int r = 0; r < RPB; ++r) {
            const float4 t = *(const float4*)&rows[r][4 * c];
            a[r] = fmaf(t.x, w0v, a[r]);
            a[r] = fmaf(t.y, w1v, a[r]);
            a[r] = fmaf(t.z, w2v, a[r]);
            a[r] = fmaf(t.w, w3v, a[r]);
        }
    }
    #pragma unroll
    for (int r = 0; r < RPB; ++r)
        part[wid][r][u] = a[r];
    __syncthreads();

    if (isq) {
        #pragma unroll
        for (int h = 0; h < 2; ++h) {
            const int p = tid + h * 256;
            const int row = p >> 6, uu = p & 63;
            const float s = (part[0][row][uu] + part[1][row][uu]) +
                            (part[2][row][uu] + part[3][row][uu]);
            Eq[(size_t)(row0 + row) * UNITS + uu] = fast_exp2(CEXP * s);
        }
    } else {
        #pragma unroll
        for (int h = 0; h < 2; ++h) {
            const int p = tid + h * 256;
            const int uu = p >> 3, r = p & 7;
            const float s = (part[0][r][uu] + part[1][r][uu]) +
                            (part[2][r][uu] + part[3][r][uu]);
            EkT[(size_t)uu * NKROW + (row0 - NQROW) + r] = fast_exp2(CEXP * s);
        }
    }
}

// ---- fused scores + softmax + context: QB=8 q-rows per block ----
// grid = NQROW/QB = 256 blocks (1 per CU), 512 threads.
// Phase A: thread owns v = {2*tid, 2*tid+1}; attn row -> LDS + out_attn.
// Phase B: thread owns (d, q-half); ctx = sum_v a_lds[q][v] * value[b][v][d].
#define QB 8
#define SNW 8
__global__ __launch_bounds__(512) void sc_kernel(
        const float* __restrict__ Eq,      // [NQROW][UNITS]
        const float* __restrict__ EkT,     // [UNITS][NKROW]
        const float* __restrict__ scale,   // [UNITS]
        const float* __restrict__ value,   // [B][TV][DV]
        float* __restrict__ out_attn,      // [NQROW][TV]
        float* __restrict__ out_ctx) {     // [NQROW][DV]
    __shared__ float a_lds[QB][TV];        // 32 KB
    __shared__ float q_lds[QB][UNITS];
    __shared__ float s_lds[UNITS];
    __shared__ float reds[QB][SNW];

    const int tid = threadIdx.x, lane = tid & 63, wid = tid >> 6;
    int bid = blockIdx.x;
    bid = (bid & 7) * ((NQROW / QB) >> 3) + (bid >> 3);   // XCD swizzle, bijective
    const int b  = bid / (TQ / QB);
    const int q0 = (bid % (TQ / QB)) * QB;

    q_lds[tid >> 6][tid & 63] =
        Eq[(size_t)(b * TQ + q0 + (tid >> 6)) * UNITS + (tid & 63)];
    if (tid < UNITS) s_lds[tid] = scale[tid];
    __syncthreads();

    // ---- phase A: scores (u-quad rcp fusion) ----
    const float* ekc = EkT + (size_t)b * TV + 2 * tid;
    float acc0[QB] = {}, acc1[QB] = {};

    #pragma unroll 2
    for (int u4 = 0; u4 < UNITS / 4; ++u4) {
        const float2 ek0 = *(const float2*)(ekc + (size_t)(4 * u4 + 0) * NKROW);
        const float2 ek1 = *(const float2*)(ekc + (size_t)(4 * u4 + 1) * NKROW);
        const float2 ek2 = *(const float2*)(ekc + (size_t)(4 * u4 + 2) * NKROW);
        const float2 ek3 = *(const float2*)(ekc + (size_t)(4 * u4 + 3) * NKROW);
        const float4 s4 = *(const float4*)(s_lds + 4 * u4);
        #pragma unroll
        for (int q = 0; q < QB; ++q) {
            const float4 eq = *(const float4*)(&q_lds[q][4 * u4]);
            {   // v0: sum_{i=0..3} s_i / t_i with one rcp
                float t0 = fmaf(eq.x, ek0.x, 1.f);
                float t1 = fmaf(eq.y, ek1.x, 1.f);
                float t2 = fmaf(eq.z, ek2.x, 1.f);
                float t3 = fmaf(eq.w, ek3.x, 1.f);
                float p01 = t0 * t1, p23 = t2 * t3;
                float A  = fmaf(s4.y, t0, s4.x * t1);
                float Bq = fmaf(s4.w, t2, s4.z * t3);
                float num = fmaf(Bq, p01, A * p23);
                float r = __builtin_amdgcn_rcpf(p01 * p23);
                acc0[q] = fmaf(num, r, acc0[q]);
            }
            {   // v1
                float t0 = fmaf(eq.x, ek0.y, 1.f);
                float t1 = fmaf(eq.y, ek1.y, 1.f);
                float t2 = fmaf(eq.z, ek2.y, 1.f);
                float t3 = fmaf(eq.w, ek3.y, 1.f);
                float p01 = t0 * t1, p23 = t2 * t3;
                float A  = fmaf(s4.y, t0, s4.x * t1);
                float Bq = fmaf(s4.w, t2, s4.z * t3);
                float num = fmaf(Bq, p01, A * p23);
                float r = __builtin_amdgcn_rcpf(p01 * p23);
                acc1[q] = fmaf(num, r, acc1[q]);
            }
        }
    }

    // ---- softmax (no-max, range-safe) + attn write + LDS stage ----
    float e0[QB], e1[QB];
    #pragma unroll
    for (int q = 0; q < QB; ++q) {
        e0[q] = fast_exp2(-2.f * LOG2E * acc0[q]);
        e1[q] = fast_exp2(-2.f * LOG2E * acc1[q]);
        float s = wave_sum(e0[q] + e1[q]);
        if (lane == 0) reds[q][wid] = s;
    }
    __syncthreads();
    #pragma unroll
    for (int q = 0; q < QB; ++q) {
        float ss = reds[q][0];
        #pragma unroll
        for (int i = 1; i < SNW; ++i) ss += reds[q][i];
        const float inv = __builtin_amdgcn_rcpf(ss);
        const float a0 = e0[q] * inv, a1 = e1[q] * inv;
        a_lds[q][2 * tid]     = a0;
        a_lds[q][2 * tid + 1] = a1;
        float2 o; o.x = a0; o.y = a1;
        *(float2*)(out_attn + (size_t)(b * TQ + q0 + q) * TV + 2 * tid) = o;
    }
    __syncthreads();

    // ---- phase B: context from LDS attn ----
    const int d  = tid & (DV - 1);
    const int qh = __builtin_amdgcn_readfirstlane(tid >> 8) * (QB / 2);
    const float* vb = value + (size_t)b * TV * DV + d;
    float acc[QB / 2] = {};
    #pragma unroll 8
    for (int v = 0; v < TV; ++v) {
        const float val = vb[(size_t)v * DV];
        #pragma unroll
        for (int j = 0; j < QB / 2; ++j)
            acc[j] = fmaf(a_lds[qh + j][v], val, acc[j]);
    }
    float* o = out_ctx + (size_t)(b * TQ + q0 + qh) * DV + d;
    #pragma unroll
    for (int j = 0; j < QB / 2; ++j)
        o[(size_t)j * DV] = acc[j];
}

extern "C" void kernel_launch(void* const* d_in, const int* in_sizes, int n_in,
                              void* d_out, int out_size, void* d_ws, size_t ws_size,
                              hipStream_t stream) {
    const float* query = (const float*)d_in[0];
    const float* value = (const float*)d_in[1];
    const float* w1    = (const float*)d_in[2];
    const float* w2    = (const float*)d_in[3];
    const float* scale = (const float*)d_in[4];

    float* out      = (float*)d_out;
    float* out_ctx  = out;                         // [NQROW*DV]
    float* out_attn = out + (size_t)NQROW * DV;    // [NQROW*TV]

    float* Eq  = (float*)d_ws;                     // NQROW*UNITS
    float* EkT = Eq + (size_t)NQROW * UNITS;       // UNITS*NKROW

    proj_kernel<<<dim3((NQROW + NKROW) / RPB), 256, 0, stream>>>(
        query, value, w1, w2, Eq, EkT);
    sc_kernel<<<dim3(NQROW / QB), 512, 0, stream>>>(
        Eq, EkT, scale, value, out_attn, out_ctx);
}